// Round 11
// baseline (96.705 us; speedup 1.0000x reference)
//
#include <hip/hip_runtime.h>
#include <math.h>

#define NDEG 64          // N
#define LDCB 67          // cBar/sBar row stride (N + 3)

#define MU_F   398600441800000.0f
#define AREF_F 6378136.3f

#define NSUB 8           // sub-waves per element group (block = 512)
#define EPW  64          // lanes per wave = elements per block
#define NREC 9           // head records per j (8 columns + m=64 tail)
#define SF4  288         // float4 entries per stream (fixed, j-independent)

// j-INDEPENDENT padded column sizes (entries) and offsets, k = 0..7:
//   len(j,k) = 63 - m(j,k) with m = j,15-j,16+j,31-j,32+j,47-j,48+j,63-j
//   len ranges: 56-63, 48-55, 40-47, 32-39, 24-31, 16-23, 8-15, 0-7
#define PAD0 64
#define PAD1 56
#define PAD2 48
#define PAD3 40
#define PAD4 32
#define PAD5 24
#define PAD6 16
#define PAD7 8
// prefix offsets (float4 units)
#define OFF0 0
#define OFF1 64
#define OFF2 120
#define OFF3 168
#define OFF4 208
#define OFF5 240
#define OFF6 264
#define OFF7 280

// 64 B group of 4 packed entries (ntilde2, ctilde, stilde, pad)
struct alignas(64) Cons4 { float4 v[4]; };

__device__ __forceinline__ int zig8(int j, int k) {
    switch (k) { case 0: return j;      case 1: return 15 - j;
                 case 2: return 16 + j; case 3: return 31 - j;
                 case 4: return 32 + j; case 5: return 47 - j;
                 case 6: return 48 + j; default: return 63 - j; }
}

// ---------------------------------------------------------------------------
// Setup: 1 block x 256.
// Threads 0..63: stream column (j = t>>3, k = t&7) at fixed offset OFFk,
// padded to PADk entries. Entry l = m+2+i (fused/rescaled — math identical
// to R9/R10 which validated absmax = 0.0):
//   ( ntilde2, ghat*cBar[l][m], ghat*sBar[l][m], 0 )
//   ntilde2 = sqrt(1/(2m+3)) at l=m+2, else (l+m-1)(l-m-1)/((2l-1)(2l-3))
//   ghat = sqrt(G), G *= (2l+1)(2l-1)/((l-m)(l+m))
// Threads 64..135: head record (j = h/9, k = h%9):
//   a = (diag[m], sub[m+1]*diag[m+1], cB[m][m]|0, sB[m][m]|0)
//   b = (cB[m+1][m]|0, sB[m+1][m]|0, 0, 0);  k=8 -> m=64 tail (j=0 only).
// ---------------------------------------------------------------------------
__global__ void pines_setup(const float* __restrict__ cBar,
                            const float* __restrict__ sBar,
                            float4* __restrict__ stream,   // NSUB*SF4 float4
                            float4* __restrict__ hrec) {   // NSUB*NREC*2 float4
    const int PADK[8] = {PAD0,PAD1,PAD2,PAD3,PAD4,PAD5,PAD6,PAD7};
    const int OFFK[8] = {OFF0,OFF1,OFF2,OFF3,OFF4,OFF5,OFF6,OFF7};
    int t = threadIdx.x;
    if (t < 64) {
        int j = t >> 3, k = t & 7;
        int m    = zig8(j, k);
        int len  = 63 - m;
        int ecap = PADK[k];
        float4* __restrict__ dst = stream + j * SF4 + OFFK[k];
        double G = 1.0;
        for (int i = 0; i < ecap; ++i) {
            float4 v = make_float4(0.0f, 0.0f, 0.0f, 0.0f);
            if (i < len) {
                int l = m + 2 + i;
                G *= (2.0 * l + 1.0) * (2.0 * l - 1.0) /
                     ((double)(l - m) * (l + m));
                double g = sqrt(G);
                double nt2 = (i == 0)
                    ? sqrt(1.0 / (2.0 * m + 3.0))
                    : ((double)(l + m - 1) * (l - m - 1)) /
                      ((double)(2 * l - 1) * (2 * l - 3));
                v = make_float4((float)nt2,
                                (float)(g * (double)cBar[l * LDCB + m]),
                                (float)(g * (double)sBar[l * LDCB + m]),
                                0.0f);
            }
            dst[i] = v;
        }
    } else if (t < 64 + NSUB * NREC) {
        int h = t - 64;
        int j = h / NREC, k = h % NREC;
        int m = (k < 8) ? zig8(j, k) : ((j == 0) ? 64 : 99);
        float4 a = make_float4(0.0f, 0.0f, 0.0f, 0.0f);
        float4 b = make_float4(0.0f, 0.0f, 0.0f, 0.0f);
        if (m <= NDEG) {
            double diag = 1.0;
            for (int l = 1; l <= m; ++l) {
                double kp = (l == 1) ? 1.0 : 2.0;   // k[l-1]
                diag *= sqrt((2.0 * l + 1.0) * 2.0 / (2.0 * l * kp));
            }
            double sd = 0.0;
            if (m < NDEG) {
                double kprev = (m == 0) ? 1.0 : 2.0;              // k[m]
                double f    = sqrt((2.0 * (m + 1) + 1.0) * 2.0 /
                                   (2.0 * (m + 1) * kprev));      // f(m+1)
                double sub1 = sqrt((double)(m + 1) * kprev);      // sub[m+1]
                sd = sub1 * diag * f;
            }
            float cmm = (m >= 1) ? cBar[m * LDCB + m] : 0.0f;
            float smm = (m >= 1) ? sBar[m * LDCB + m] : 0.0f;
            float cb1 = (m < NDEG) ? cBar[(m + 1) * LDCB + m] : 0.0f;
            float sb1 = (m < NDEG) ? sBar[(m + 1) * LDCB + m] : 0.0f;
            a = make_float4((float)diag, (float)sd, cmm, smm);
            b = make_float4(cb1, sb1, 0.0f, 0.0f);
        }
        hrec[h * 2]     = a;
        hrec[h * 2 + 1] = b;
    }
}

// ---------------------------------------------------------------------------
// Main kernel. Block = 512 = 8 waves; wave j = sub index; lanes = 64
// elements. The ENTIRE per-wave instruction stream is compile-time constant:
// padded column sizes are j-independent, so all trip counts and stream/head
// offsets are immediates. Fully unrolled -> no loop branches, no ntr/g SALU,
// no readfirstlane in the hot path; the compiler hoists s_load batches
// several trips deep (fewer lgkmcnt drains) and schedules freely.
// Recursion (fused, validated absmax=0.0 in R9/R10):
//   q^ = fma(ur, q1, -rho2*(nt2*q0)); contrib ctilde/stilde; mu/r at store.
// Pad entries (all-zero) are inert; recursion state resets each column.
// ---------------------------------------------------------------------------
__global__ __launch_bounds__(512, 8) void pines_kernel(
        const float4* __restrict__ inputs,
        const float4* __restrict__ stream,
        const float4* __restrict__ hrec,
        float* __restrict__ out, int B) {
    const int PADK[8] = {PAD0,PAD1,PAD2,PAD3,PAD4,PAD5,PAD6,PAD7};
    const int OFFK[8] = {OFF0,OFF1,OFF2,OFF3,OFF4,OFF5,OFF6,OFF7};
    __shared__ float part[NSUB][EPW];

    int t = threadIdx.x;
    int j = __builtin_amdgcn_readfirstlane(t >> 6);
    int e = t & (EPW - 1);
    int elem = blockIdx.x * EPW + e;
    int lelem = elem < B ? elem : (B - 1);

    float4 in = inputs[lelem];
    float r = in.x, ss = in.y, tt = in.z, u = in.w;

    float rho   = AREF_F / r;
    float rho2  = rho * rho;
    float nrho2 = -rho2;
    float ur    = u * rho;

    int d1 = 15 - 2 * j;
    int d2 = 1 + 2 * j;

    auto cpow = [&](int e_, float& re_, float& im_) {
        float br = ss, bi = tt;
        re_ = 1.0f; im_ = 0.0f;
        int ee = e_;
        while (ee) {
            if (ee & 1) {
                float nr = re_ * br - im_ * bi;
                im_ = re_ * bi + im_ * br;
                re_ = nr;
            }
            float sr = br * br - bi * bi;
            bi = 2.0f * br * bi;
            br = sr;
            ee >>= 1;
        }
    };
    auto rpow = [&](int e_) {
        float b = rho, acc = 1.0f;
        int ee = e_;
        while (ee) {
            if (ee & 1) acc *= b;
            b *= b;
            ee >>= 1;
        }
        return acc;
    };

    float re, im;      cpow(j, re, im);
    float s1r, s1i;    cpow(d1, s1r, s1i);
    float s2r, s2i;    cpow(d2, s2r, s2i);
    float rstep1 = rpow(d1);
    float rstep2 = rpow(d2);
    float rho_m  = rpow(j);              // rho^m at m = j

    float sum = (j == 0) ? 1.0f : 0.0f;  // l = 0 term (times mu/r at end)

    const float4* __restrict__ hp = hrec + j * NREC * 2;
    const Cons4*  __restrict__ sp = (const Cons4*)(stream + j * SF4);

    #pragma unroll
    for (int k = 0; k < 8; ++k) {
        float4 h0 = hp[2 * k];           // constant offsets; compiler hoists
        float4 h1 = hp[2 * k + 1];

        float q0 = h0.x * rho_m;                       // q at l = m
        float sA = q0 * h0.z;
        float sB = q0 * h0.w;
        float q1 = (h0.y * u) * (rho_m * rho);         // q at l = m+1
        sA = fmaf(q1, h1.x, sA);
        sB = fmaf(q1, h1.y, sB);

        const int ntr = PADK[k] >> 3;                  // compile-time
        #pragma unroll
        for (int tr = 0; tr < ntr; ++tr) {
            Cons4 ca = sp[(OFFK[k] >> 2) + 2 * tr];     // imm-offset s_loads
            Cons4 cb = sp[(OFFK[k] >> 2) + 2 * tr + 1];
            #pragma unroll
            for (int q4 = 0; q4 < 4; ++q4) {
                float4 cc = ca.v[q4];
                float t3 = cc.x * q0;
                float t4 = nrho2 * t3;
                float q  = fmaf(ur, q1, t4);
                sA = fmaf(q, cc.y, sA);
                sB = fmaf(q, cc.z, sB);
                q0 = q1; q1 = q;
            }
            #pragma unroll
            for (int q4 = 0; q4 < 4; ++q4) {
                float4 cc = cb.v[q4];
                float t3 = cc.x * q0;
                float t4 = nrho2 * t3;
                float q  = fmaf(ur, q1, t4);
                sA = fmaf(q, cc.y, sA);
                sB = fmaf(q, cc.z, sB);
                q0 = q1; q1 = q;
            }
        }
        sum = fmaf(re, sA, sum);
        sum = fmaf(im, sB, sum);

        // advance to next column: even k -> *step(d1), odd k -> *step(d2)
        if (k & 1) {
            float nr = re * s2r - im * s2i;
            im = re * s2i + im * s2r; re = nr;
            rho_m *= rstep2;
        } else {
            float nr = re * s1r - im * s1i;
            im = re * s1i + im * s1r; re = nr;
            rho_m *= rstep1;
        }
    }
    // m=64 diagonal tail: after k=7 the state advanced to m = 64+j; record 8
    // is zeros for j!=0, so the garbage powers are inert.
    {
        float4 h0 = hp[16];
        float q0 = h0.x * rho_m;
        sum = fmaf(re * q0, h0.z, sum);
        sum = fmaf(im * q0, h0.w, sum);
    }

    part[j][e] = sum;
    __syncthreads();
    if (j == 0) {
        float tot = 0.0f;
        #pragma unroll
        for (int q = 0; q < NSUB; ++q) tot += part[q][e];
        if (elem < B) out[elem] = -(MU_F / r) * tot;
    }
}

extern "C" void kernel_launch(void* const* d_in, const int* in_sizes, int n_in,
                              void* d_out, int out_size, void* d_ws, size_t ws_size,
                              hipStream_t stream_h) {
    const float* inputs = (const float*)d_in[0];   // (B, 4)
    const float* cBar   = (const float*)d_in[1];   // (67, 67)
    const float* sBar   = (const float*)d_in[2];   // (67, 67)
    float* out = (float*)d_out;
    int B = in_sizes[0] / 4;

    float4* strm = (float4*)d_ws;                  // NSUB*SF4 = 2304 float4
    float4* hrec = strm + NSUB * SF4;              // NSUB*NREC*2 = 144 float4

    hipLaunchKernelGGL(pines_setup, dim3(1), dim3(256), 0, stream_h,
                       cBar, sBar, strm, hrec);

    int blocks = (B + EPW - 1) / EPW;
    hipLaunchKernelGGL(pines_kernel, dim3(blocks), dim3(512), 0, stream_h,
                       (const float4*)inputs, strm, hrec, out, B);
}